// Round 1
// baseline (398.155 us; speedup 1.0000x reference)
//
#include <hip/hip_runtime.h>

namespace {

constexpr int Hc = 32;   // heads
constexpr int Ec = 64;   // E (and D)
constexpr float EPS = 1e-6f;
constexpr float SCALE = 0.02209708691207961f;  // 2048^{-1/2}
constexpr int LDR = Ec + 4;  // pad keeps 16B alignment; 2-way bank alias is free

__device__ __forceinline__ float elu1(float x) {
    // elu(x) + 1 == (x > 0) ? x + 1 : exp(x)
    return x > 0.f ? x + 1.f : __expf(x);
}

__global__ __launch_bounds__(256, 3)
void linattn_kernel(const float* __restrict__ Q,
                    const float* __restrict__ K,
                    const float* __restrict__ V,
                    float* __restrict__ O)
{
    __shared__ float s_kf[Hc][LDR];   // elu(K)+1
    __shared__ float s_v [Hc][LDR];   // V
    __shared__ float s_qf[Hc][LDR];   // elu(Q)+1
    __shared__ float s_kv[Ec][LDR];   // kf^T @ V * SCALE
    __shared__ float s_ksum[Ec];
    __shared__ float s_y[Hc];

    const int tid  = threadIdx.x;
    const int base = blockIdx.x * (Hc * Ec);   // per-(b,l) contiguous 2048-float chunk

    const float4* q4 = reinterpret_cast<const float4*>(Q + base);
    const float4* k4 = reinterpret_cast<const float4*>(K + base);
    const float4* v4 = reinterpret_cast<const float4*>(V + base);

    // ---- Stage Q,K,V into LDS with fused elu+1 (coalesced float4) ----
    #pragma unroll
    for (int i = 0; i < 2; ++i) {
        const int idx = tid + i * 256;       // float4 index 0..511
        const int h   = idx >> 4;            // 16 float4 per row of 64
        const int e4  = (idx & 15) << 2;
        float4 kk = k4[idx];
        float4 qq = q4[idx];
        float4 vv = v4[idx];
        kk.x = elu1(kk.x); kk.y = elu1(kk.y); kk.z = elu1(kk.z); kk.w = elu1(kk.w);
        qq.x = elu1(qq.x); qq.y = elu1(qq.y); qq.z = elu1(qq.z); qq.w = elu1(qq.w);
        *reinterpret_cast<float4*>(&s_kf[h][e4]) = kk;
        *reinterpret_cast<float4*>(&s_qf[h][e4]) = qq;
        *reinterpret_cast<float4*>(&s_v [h][e4]) = vv;
    }
    __syncthreads();

    // ---- ksum[e] = sum_h kf[h][e]  (64 lanes; read after next barrier) ----
    if (tid < Ec) {
        float s = 0.f;
        #pragma unroll
        for (int h = 0; h < Hc; ++h) s += s_kf[h][tid];
        s_ksum[tid] = s;
    }

    // ---- kv[e][d] = sum_h kf[h][e] * v[h][d]; 4x4 register tile per thread ----
    const int ty = tid >> 4;       // 0..15
    const int tx = tid & 15;       // 0..15
    const int e0 = ty << 2;
    const int d0 = tx << 2;

    float acc[4][4] = {};
    #pragma unroll
    for (int h = 0; h < Hc; ++h) {
        const float4 a = *reinterpret_cast<const float4*>(&s_kf[h][e0]);
        const float4 b = *reinterpret_cast<const float4*>(&s_v [h][d0]);
        const float av[4] = {a.x, a.y, a.z, a.w};
        const float bv[4] = {b.x, b.y, b.z, b.w};
        #pragma unroll
        for (int i = 0; i < 4; ++i)
            #pragma unroll
            for (int j = 0; j < 4; ++j)
                acc[i][j] = fmaf(av[i], bv[j], acc[i][j]);
    }
    #pragma unroll
    for (int i = 0; i < 4; ++i) {
        float4 r;
        r.x = acc[i][0] * SCALE;
        r.y = acc[i][1] * SCALE;
        r.z = acc[i][2] * SCALE;
        r.w = acc[i][3] * SCALE;
        *reinterpret_cast<float4*>(&s_kv[e0 + i][d0]) = r;
    }
    __syncthreads();

    // ---- y[h] = 1/(qf[h]·ksum + eps) ----
    if (tid < Hc) {
        float s = 0.f;
        #pragma unroll
        for (int e = 0; e < Ec; ++e) s = fmaf(s_qf[tid][e], s_ksum[e], s);
        s_y[tid] = 1.f / (s + EPS);
    }
    __syncthreads();

    // ---- x[h][d] = (qf @ kv)[h][d] * y[h]; 2x4 register tile per thread ----
    const int h0 = ty << 1;
    float xo[2][4] = {};
    #pragma unroll
    for (int e = 0; e < Ec; e += 4) {
        const float4 a0 = *reinterpret_cast<const float4*>(&s_qf[h0    ][e]);
        const float4 a1 = *reinterpret_cast<const float4*>(&s_qf[h0 + 1][e]);
        const float4 b0 = *reinterpret_cast<const float4*>(&s_kv[e + 0][d0]);
        const float4 b1 = *reinterpret_cast<const float4*>(&s_kv[e + 1][d0]);
        const float4 b2 = *reinterpret_cast<const float4*>(&s_kv[e + 2][d0]);
        const float4 b3 = *reinterpret_cast<const float4*>(&s_kv[e + 3][d0]);
        const float a0v[4] = {a0.x, a0.y, a0.z, a0.w};
        const float a1v[4] = {a1.x, a1.y, a1.z, a1.w};
        const float bm[4][4] = {
            {b0.x, b0.y, b0.z, b0.w},
            {b1.x, b1.y, b1.z, b1.w},
            {b2.x, b2.y, b2.z, b2.w},
            {b3.x, b3.y, b3.z, b3.w},
        };
        #pragma unroll
        for (int j = 0; j < 4; ++j)
            #pragma unroll
            for (int d = 0; d < 4; ++d) {
                xo[0][d] = fmaf(a0v[j], bm[j][d], xo[0][d]);
                xo[1][d] = fmaf(a1v[j], bm[j][d], xo[1][d]);
            }
    }

    const float y0 = s_y[h0];
    const float y1 = s_y[h0 + 1];
    float4 o0, o1;
    o0.x = xo[0][0] * y0; o0.y = xo[0][1] * y0; o0.z = xo[0][2] * y0; o0.w = xo[0][3] * y0;
    o1.x = xo[1][0] * y1; o1.y = xo[1][1] * y1; o1.z = xo[1][2] * y1; o1.w = xo[1][3] * y1;

    float4* out4 = reinterpret_cast<float4*>(O + base);
    out4[ h0      * 16 + tx] = o0;
    out4[(h0 + 1) * 16 + tx] = o1;
}

}  // namespace

extern "C" void kernel_launch(void* const* d_in, const int* in_sizes, int n_in,
                              void* d_out, int out_size, void* d_ws, size_t ws_size,
                              hipStream_t stream) {
    const float* Q = reinterpret_cast<const float*>(d_in[0]);
    const float* K = reinterpret_cast<const float*>(d_in[1]);
    const float* V = reinterpret_cast<const float*>(d_in[2]);
    float* O = reinterpret_cast<float*>(d_out);

    const int n_bl = in_sizes[0] / (Hc * Ec);   // B*L = 16384 blocks
    linattn_kernel<<<n_bl, 256, 0, stream>>>(Q, K, V, O);
}